// Round 12
// baseline (717.346 us; speedup 1.0000x reference)
//
#include <hip/hip_runtime.h>

#define N_NODES 50000
#define N_EDGES 400000
#define M_PAD   50176   // 196 * 256
#define SCAN_B  196
#define EPS_BN  1e-5f

typedef short bf16x8 __attribute__((ext_vector_type(8)));
typedef float f32x4 __attribute__((ext_vector_type(4)));

__device__ __forceinline__ float bf2f(unsigned short h) {
  union { unsigned int u; float f; } v; v.u = ((unsigned int)h) << 16; return v.f;
}
__device__ __forceinline__ unsigned short f2bf(float x) {
  union { float f; unsigned int u; } v; v.f = x;
  unsigned int r = v.u + 0x7FFFu + ((v.u >> 16) & 1u);
  return (unsigned short)(r >> 16);
}

// ---------------- CSR build ----------------
__global__ void count_deg(const int* __restrict__ dst, int* __restrict__ deg) {
  int e = blockIdx.x * 256 + threadIdx.x;
  if (e < N_EDGES) {
    int d = dst[e];
    if (d >= 0 && d < N_NODES) atomicAdd(&deg[d], 1);
  }
}

__global__ void block_sums(const int* __restrict__ deg, int* __restrict__ bsum) {
  __shared__ int sd[256];
  int b = blockIdx.x, t = threadIdx.x;
  int i = b * 256 + t;
  sd[t] = (i < N_NODES) ? deg[i] : 0;
  __syncthreads();
  for (int off = 128; off > 0; off >>= 1) {
    if (t < off) sd[t] += sd[t + off];
    __syncthreads();
  }
  if (t == 0) bsum[b] = sd[0];
}

__global__ void scan_bsums(const int* __restrict__ bsum, int* __restrict__ boff) {
  __shared__ int sd[256];
  int t = threadIdx.x;
  int v = (t < SCAN_B) ? bsum[t] : 0;
  sd[t] = v;
  __syncthreads();
  for (int off = 1; off < 256; off <<= 1) {
    int add = (t >= off) ? sd[t - off] : 0;
    __syncthreads();
    sd[t] += add;
    __syncthreads();
  }
  if (t < SCAN_B) boff[t] = sd[t] - v;  // exclusive
}

__global__ void write_rowptr(const int* __restrict__ deg, const int* __restrict__ boff,
                             int* __restrict__ row_ptr, int* __restrict__ cursor) {
  __shared__ int sd[256];
  int b = blockIdx.x, t = threadIdx.x;
  int i = b * 256 + t;
  int v = (i < N_NODES) ? deg[i] : 0;
  sd[t] = v;
  __syncthreads();
  for (int off = 1; off < 256; off <<= 1) {
    int add = (t >= off) ? sd[t - off] : 0;
    __syncthreads();
    sd[t] += add;
    __syncthreads();
  }
  if (i < N_NODES) {
    int ex = boff[b] + sd[t] - v;
    row_ptr[i] = ex;
    cursor[i]  = ex;
    if (i == N_NODES - 1) row_ptr[N_NODES] = boff[b] + sd[t];
  }
}

__global__ void scatter_edges(const int* __restrict__ src, const int* __restrict__ dst,
                              int* __restrict__ cursor, int* __restrict__ esrc) {
  int e = blockIdx.x * 256 + threadIdx.x;
  if (e < N_EDGES) {
    int d = dst[e];
    int s = src[e];
    if (d >= 0 && d < N_NODES && s >= 0 && s < N_NODES) {
      int p = atomicAdd(&cursor[d], 1);
      esrc[p] = s;
    }
  }
}

// ---------------- weight packs ----------------
__global__ void pack_wt(const float* __restrict__ Wl, const float* __restrict__ Wr,
                        unsigned short* __restrict__ WT, int Keach, int N, int Npad, int Kpad) {
  int idx = blockIdx.x * 256 + threadIdx.x;
  if (idx >= Npad * Kpad) return;
  int n = idx / Kpad, k = idx % Kpad;
  float v = 0.f;
  if (n < N) {
    if (k < Keach) v = Wl[k * N + n];
    else if (k < 2 * Keach) v = Wr[(k - Keach) * N + n];
  }
  WT[idx] = f2bf(v);
}

__global__ void pack_w1(const float* __restrict__ W, unsigned short* __restrict__ WT, int K,
                        int N, int Npad, int Kpad) {
  int idx = blockIdx.x * 256 + threadIdx.x;
  if (idx >= Npad * Kpad) return;
  int n = idx / Kpad, k = idx % Kpad;
  float v = (n < N && k < K) ? W[k * N + n] : 0.f;
  WT[idx] = f2bf(v);
}

// ---------------- layer-1 input build ----------------
__global__ void prep1v(const float* __restrict__ x, const int* __restrict__ row_ptr,
                       const int* __restrict__ esrc, unsigned short* __restrict__ cat1) {
  __shared__ float part[4][64];
  int n = blockIdx.x, t = threadIdx.x;
  int w = t >> 6, lane = t & 63;
  unsigned short* row = cat1 + (long)n * 128;
  if (n >= N_NODES) {
    if (t < 64) { row[t] = 0; row[64 + t] = 0; }
    return;
  }
  int e0 = row_ptr[n], e1 = row_ptr[n + 1];
  float acc = 0.f;
  if (lane < 50) {
    for (int e = e0 + w; e < e1; e += 4) acc += x[(long)esrc[e] * 50 + lane];
  }
  part[w][lane] = acc;
  __syncthreads();
  if (t < 128) {
    if (t < 64) {
      float s = part[0][t] + part[1][t] + part[2][t] + part[3][t];
      float rdeg = (e1 > e0) ? 1.f / (float)(e1 - e0) : 0.f;
      if (t < 50) {
        row[t]      = f2bf(s * rdeg);
        row[50 + t] = f2bf(x[(long)n * 50 + t]);
      }
    } else if (t >= 100) {
      row[t] = 0;
    }
  }
}

// ---------------- mean aggregation, 512 cols: wave-per-node, 2-edge unroll ------------
__global__ void agg_mean512(const int* __restrict__ row_ptr, const int* __restrict__ esrc,
                            const unsigned short* __restrict__ h,
                            unsigned short* __restrict__ agg) {
  int n = blockIdx.x * 4 + (threadIdx.x >> 6);
  int lane = threadIdx.x & 63;
  if (n >= M_PAD) return;
  uint2* outw = (uint2*)(agg + (long)n * 512 + lane * 8);
  if (n >= N_NODES) {
    uint2 z; z.x = 0; z.y = 0;
    outw[0] = z; outw[1] = z;
    return;
  }
  int e0 = row_ptr[n], e1 = row_ptr[n + 1];
  float acc[8] = {0.f, 0.f, 0.f, 0.f, 0.f, 0.f, 0.f, 0.f};
  int e = e0;
  for (; e + 1 < e1; e += 2) {
    int s0 = esrc[e], s1 = esrc[e + 1];
    uint4 v0 = *(const uint4*)(h + (long)s0 * 512 + lane * 8);
    uint4 v1 = *(const uint4*)(h + (long)s1 * 512 + lane * 8);
    const unsigned short* p0 = (const unsigned short*)&v0;
    const unsigned short* p1 = (const unsigned short*)&v1;
#pragma unroll
    for (int j = 0; j < 8; ++j) acc[j] += bf2f(p0[j]) + bf2f(p1[j]);
  }
  if (e < e1) {
    uint4 v0 = *(const uint4*)(h + (long)esrc[e] * 512 + lane * 8);
    const unsigned short* p0 = (const unsigned short*)&v0;
#pragma unroll
    for (int j = 0; j < 8; ++j) acc[j] += bf2f(p0[j]);
  }
  float rdeg = (e1 > e0) ? 1.f / (float)(e1 - e0) : 0.f;
  uint2 r0, r1;
  r0.x = (unsigned int)f2bf(acc[0] * rdeg) | ((unsigned int)f2bf(acc[1] * rdeg) << 16);
  r0.y = (unsigned int)f2bf(acc[2] * rdeg) | ((unsigned int)f2bf(acc[3] * rdeg) << 16);
  r1.x = (unsigned int)f2bf(acc[4] * rdeg) | ((unsigned int)f2bf(acc[5] * rdeg) << 16);
  r1.y = (unsigned int)f2bf(acc[6] * rdeg) | ((unsigned int)f2bf(acc[7] * rdeg) << 16);
  outw[0] = r0;
  outw[1] = r1;
}

// ---------------- layer-4 gather-add, 121 cols ----------------
__global__ void agg_add121(const int* __restrict__ row_ptr, const int* __restrict__ esrc,
                           const unsigned short* __restrict__ t4, float* __restrict__ out) {
  int n = blockIdx.x * 4 + (threadIdx.x >> 6);
  if (n >= N_NODES) return;
  int lane = threadIdx.x & 63;
  int g = lane >> 4;
  int cl = lane & 15;
  int e0 = row_ptr[n], e1 = row_ptr[n + 1];
  float acc[8] = {0.f, 0.f, 0.f, 0.f, 0.f, 0.f, 0.f, 0.f};
  for (int e = e0 + g; e < e1; e += 4) {
    int s = esrc[e];
    uint4 v = *(const uint4*)(t4 + (long)s * 128 + cl * 8);
    const unsigned short* pv = (const unsigned short*)&v;
#pragma unroll
    for (int j = 0; j < 8; ++j) acc[j] += bf2f(pv[j]);
  }
#pragma unroll
  for (int j = 0; j < 8; ++j) {
    acc[j] += __shfl_xor(acc[j], 16);
    acc[j] += __shfl_xor(acc[j], 32);
  }
  if (g == 0) {
    float rdeg = (e1 > e0) ? 1.f / (float)(e1 - e0) : 0.f;
#pragma unroll
    for (int j = 0; j < 8; ++j) {
      int c = cl * 8 + j;
      if (c < 121) out[(long)n * 121 + c] += acc[j] * rdeg;
    }
  }
}

// ---------------- BN finalize / apply+ReLU ----------------
__global__ void bn_finalize(const float* __restrict__ ssum, const float* __restrict__ ssq,
                            const float* __restrict__ g, const float* __restrict__ b,
                            float* __restrict__ scale, float* __restrict__ shiftv) {
  int c = threadIdx.x;
  float mu  = ssum[c] * (1.f / N_NODES);
  float var = ssq[c] * (1.f / N_NODES) - mu * mu;
  float rs  = rsqrtf(var + EPS_BN);
  float sc  = g[c] * rs;
  scale[c]  = sc;
  shiftv[c] = b[c] - mu * sc;
}

__global__ void bn_relu(const unsigned short* __restrict__ y, const float* __restrict__ scale,
                        const float* __restrict__ shiftv, unsigned short* __restrict__ hout) {
  long idx = ((long)blockIdx.x * 256 + threadIdx.x) * 8;
  if (idx >= (long)M_PAD * 512) return;
  int row = (int)(idx >> 9);
  int col = (int)(idx & 511);
  unsigned short* o = hout + idx;
  if (row >= N_NODES) {
    uint4 z; z.x = 0; z.y = 0; z.z = 0; z.w = 0;
    *(uint4*)o = z;
    return;
  }
  uint4 v = *(const uint4*)(y + idx);
  unsigned short* p = (unsigned short*)&v;
  uint4 rr;
  unsigned short* q = (unsigned short*)&rr;
#pragma unroll
  for (int j = 0; j < 8; ++j) {
    float f = bf2f(p[j]) * scale[col + j] + shiftv[col + j];
    q[j] = f2bf(fmaxf(f, 0.f));
  }
  *(uint4*)o = rr;
}

// ---------------- 256x128 bf16 MFMA GEMM, 3-buf counted-vmcnt pipeline (T1+T2+T4) --------
// A row-major [M][lda] in two column-halves (A0: k<KA0, A1: k>=KA0); B as BT[N][K].
// 8 waves (4M x 2N), per-wave C = 64x64 (acc 64 f32). LDS 144KB: 3 x (A 32K + B 16K).
// Per tile t: vmcnt(6) [drain stage t, let t+1 ride] -> s_barrier -> issue stage(t+2)
// [its buffer's readers (tile t-1) are behind this barrier] -> compute t.
__device__ __forceinline__ void gl_lds16(const void* g, void* l) {
  __builtin_amdgcn_global_load_lds((const __attribute__((address_space(1))) unsigned int*)g,
                                   (__attribute__((address_space(3))) unsigned int*)l, 16, 0, 0);
}

__device__ __forceinline__ void stage_half(const unsigned short* srck, int ld, long row0,
                                           char* ldshalf, int q0) {
#pragma unroll
  for (int r = 0; r < 2; ++r) {
    int q = q0 + r * 8192;
    int row = q >> 7;
    int cus = ((q & 127) >> 1) ^ ((row & 7) << 3);  // inverse-swizzled source col (ushort)
    gl_lds16(srck + (row0 + row) * (long)ld + cus, ldshalf + q);
  }
}

__device__ __forceinline__ bf16x8 frag(const char* base, int lr, int cb) {
  return *(const bf16x8*)(base + lr * 128 + (cb ^ ((lr & 7) << 4)));
}

template <int MODE>
__launch_bounds__(512, 2)
__global__ void gemmpipe(int nblk, const unsigned short* __restrict__ A0,
                         const unsigned short* __restrict__ A1, int lda, int KA0,
                         const unsigned short* __restrict__ BT, int K,
                         const float* __restrict__ bias, unsigned short* __restrict__ outb,
                         int ldob, float* __restrict__ outf, float* __restrict__ ssum,
                         float* __restrict__ ssq) {
  extern __shared__ char smem[];

  // T1: bijective XCD-chunk swizzle
  const int nwg = gridDim.x, orig = blockIdx.x;
  const int xcd = orig & 7, sidx = orig >> 3;
  const int q8 = nwg >> 3, r8 = nwg & 7;
  const int wg = ((xcd < r8) ? xcd * (q8 + 1) : r8 * (q8 + 1) + (xcd - r8) * q8) + sidx;
  const int bm = wg / nblk, bn = wg - bm * nblk;
  const long brow = (long)bm * 256;
  const int bcol = bn * 128;

  const int t = threadIdx.x;
  const int lane = t & 63, wid = t >> 6;
  const int wr = (wid >> 1) * 64;   // 0,64,128,192
  const int wc = (wid & 1) * 64;    // 0,64
  const int l15 = lane & 15, l4 = lane >> 4;
  const int q0 = t * 16;

  f32x4 acc[4][4] = {};
  const int NT = K / 64;

  auto issue = [&](int tt) {
    const int k0 = tt * 64;
    const unsigned short* Ap = (k0 < KA0) ? A0 + k0 : A1 + (k0 - KA0);
    const unsigned short* Bp = BT + k0;
    char* ab = smem + (tt % 3) * 49152;
    stage_half(Ap, lda, brow, ab, q0);
    stage_half(Ap, lda, brow + 128, ab + 16384, q0);
    stage_half(Bp, K, bcol, ab + 32768, q0);
  };

  issue(0);
  if (NT > 1) issue(1);

  for (int tt = 0; tt < NT; ++tt) {
    if (tt + 1 < NT)
      asm volatile("s_waitcnt vmcnt(6)" ::: "memory");
    else
      asm volatile("s_waitcnt vmcnt(0)" ::: "memory");
    __builtin_amdgcn_s_barrier();
    if (tt + 2 < NT) issue(tt + 2);

    const char* Ard = smem + (tt % 3) * 49152;
    const char* Brd = Ard + 32768;

    bf16x8 bfr[4][2];
#pragma unroll
    for (int n = 0; n < 4; ++n)
#pragma unroll
      for (int kk = 0; kk < 2; ++kk)
        bfr[n][kk] = frag(Brd, wc + n * 16 + l15, kk * 64 + l4 * 16);
#pragma unroll
    for (int m = 0; m < 4; ++m) {
      bf16x8 af0 = frag(Ard, wr + m * 16 + l15, l4 * 16);
      bf16x8 af1 = frag(Ard, wr + m * 16 + l15, 64 + l4 * 16);
#pragma unroll
      for (int n = 0; n < 4; ++n) {
        acc[m][n] = __builtin_amdgcn_mfma_f32_16x16x32_bf16(af0, bfr[n][0], acc[m][n], 0, 0, 0);
        acc[m][n] = __builtin_amdgcn_mfma_f32_16x16x32_bf16(af1, bfr[n][1], acc[m][n], 0, 0, 0);
      }
    }
  }

  __syncthreads();  // all waves done with LDS before stats reuse

  // ---------------- epilogue ----------------
  float* sstat = (float*)smem;
  if (MODE == 0) {
    if (t < 256) sstat[t] = 0.f;
    __syncthreads();
  }

#pragma unroll
  for (int m = 0; m < 4; ++m) {
    int row0 = (int)brow + wr + m * 16 + l4 * 4;
#pragma unroll
    for (int n = 0; n < 4; ++n) {
      int col = bcol + wc + n * 16 + l15;
      if (MODE == 0) {
        float bs = bias[col];
#pragma unroll
        for (int j = 0; j < 4; ++j)
          outb[(long)(row0 + j) * ldob + col] = f2bf(acc[m][n][j] + bs);
      } else {
        if (col < 128) {
#pragma unroll
          for (int j = 0; j < 4; ++j)
            outb[(long)(row0 + j) * ldob + col] = f2bf(acc[m][n][j]);
        } else {
          int c2 = col - 128;
          if (c2 < 121) {
            float bs = bias[c2];
#pragma unroll
            for (int j = 0; j < 4; ++j) {
              int row = row0 + j;
              if (row < N_NODES) outf[(long)row * 121 + c2] = acc[m][n][j] + bs;
            }
          }
        }
      }
    }
  }

  if (MODE == 0) {
#pragma unroll
    for (int n = 0; n < 4; ++n) {
      int colL = wc + n * 16 + l15;
      float bs = bias[bcol + colL];
      float s = 0.f, s2 = 0.f;
#pragma unroll
      for (int m = 0; m < 4; ++m) {
        int row0 = (int)brow + wr + m * 16 + l4 * 4;
#pragma unroll
        for (int j = 0; j < 4; ++j) {
          if (row0 + j < N_NODES) {
            float v = acc[m][n][j] + bs;
            s += v;
            s2 += v * v;
          }
        }
      }
      atomicAdd(&sstat[colL], s);
      atomicAdd(&sstat[128 + colL], s2);
    }
    __syncthreads();
    if (t < 128) {
      atomicAdd(&ssum[bcol + t], sstat[t]);
      atomicAdd(&ssq[bcol + t], sstat[128 + t]);
    }
  }
}

// ---------------- host launcher ----------------
extern "C" void kernel_launch(void* const* d_in, const int* in_sizes, int n_in, void* d_out,
                              int out_size, void* d_ws, size_t ws_size, hipStream_t stream) {
  char* p = (char*)d_ws;
  auto take = [&](size_t b) {
    char* r = p;
    p += (b + 255) & ~(size_t)255;
    return r;
  };
  int* deg      = (int*)take((size_t)N_NODES * 4);
  int* row_ptr  = (int*)take((size_t)(N_NODES + 4) * 4);
  int* cursor   = (int*)take((size_t)N_NODES * 4);
  int* esrc     = (int*)take((size_t)N_EDGES * 4);
  int* bsum     = (int*)take(256 * 4);
  int* boffb    = (int*)take(256 * 4);
  unsigned short* W1T = (unsigned short*)take((size_t)512 * 128 * 2);
  unsigned short* W2T = (unsigned short*)take((size_t)512 * 1024 * 2);
  unsigned short* W3T = (unsigned short*)take((size_t)512 * 1024 * 2);
  unsigned short* W4T = (unsigned short*)take((size_t)256 * 512 * 2);  // [Wl4^T;Wr4^T]
  float* ssum   = (float*)take(512 * 4);
  float* ssq    = (float*)take(512 * 4);
  float* scale  = (float*)take(512 * 4);
  float* shiftv = (float*)take(512 * 4);
  unsigned short* abuf = (unsigned short*)take((size_t)M_PAD * 512 * 2);
  unsigned short* ybuf = (unsigned short*)take((size_t)M_PAD * 512 * 2);
  unsigned short* hbuf = (unsigned short*)take((size_t)M_PAD * 512 * 2);

  size_t need = (size_t)(p - (char*)d_ws);
  if (need > ws_size || n_in < 20) {
    hipMemsetAsync(d_out, 0, (size_t)out_size * 4, stream);
    return;
  }

  const float* x   = (const float*)d_in[0];
  const int*   ei  = (const int*)d_in[1];
  const int*   srcv = ei;
  const int*   dstv = ei + N_EDGES;
  const float* Wl1 = (const float*)d_in[2];
  const float* bl1 = (const float*)d_in[3];
  const float* Wr1 = (const float*)d_in[4];
  const float* Wl2 = (const float*)d_in[5];
  const float* bl2 = (const float*)d_in[6];
  const float* Wr2 = (const float*)d_in[7];
  const float* Wl3 = (const float*)d_in[8];
  const float* bl3 = (const float*)d_in[9];
  const float* Wr3 = (const float*)d_in[10];
  const float* Wl4 = (const float*)d_in[11];
  const float* bl4 = (const float*)d_in[12];
  const float* Wr4 = (const float*)d_in[13];
  const float* g1  = (const float*)d_in[14];
  const float* b1  = (const float*)d_in[15];
  const float* g2  = (const float*)d_in[16];
  const float* b2  = (const float*)d_in[17];
  const float* g3  = (const float*)d_in[18];
  const float* b3  = (const float*)d_in[19];

  // CSR (parallel scan)
  hipMemsetAsync(deg, 0, (size_t)N_NODES * 4, stream);
  count_deg<<<(N_EDGES + 255) / 256, 256, 0, stream>>>(dstv, deg);
  block_sums<<<SCAN_B, 256, 0, stream>>>(deg, bsum);
  scan_bsums<<<1, 256, 0, stream>>>(bsum, boffb);
  write_rowptr<<<SCAN_B, 256, 0, stream>>>(deg, boffb, row_ptr, cursor);
  scatter_edges<<<(N_EDGES + 255) / 256, 256, 0, stream>>>(srcv, dstv, cursor, esrc);

  // weights
  pack_wt<<<(512 * 128 + 255) / 256, 256, 0, stream>>>(Wl1, Wr1, W1T, 50, 512, 512, 128);
  pack_wt<<<(512 * 1024 + 255) / 256, 256, 0, stream>>>(Wl2, Wr2, W2T, 512, 512, 512, 1024);
  pack_wt<<<(512 * 1024 + 255) / 256, 256, 0, stream>>>(Wl3, Wr3, W3T, 512, 512, 512, 1024);
  pack_w1<<<(128 * 512 + 255) / 256, 256, 0, stream>>>(Wl4, W4T, 512, 121, 128, 512);
  pack_w1<<<(128 * 512 + 255) / 256, 256, 0, stream>>>(Wr4, W4T + 128 * 512, 512, 121, 128, 512);

  const int g23 = 196 * 4;           // 256-row panels x 4 col-blocks (128 cols each)
  const size_t LDSB = 147456;        // 3 x 48KB
  int bn_blocks = (int)(((long)M_PAD * 512 / 8) / 256);
  int agg_blocks = M_PAD / 4;

  // ---- layer 1 ----
  prep1v<<<M_PAD, 256, 0, stream>>>(x, row_ptr, esrc, abuf);
  hipMemsetAsync(ssum, 0, 4096, stream);  // ssum+ssq contiguous
  gemmpipe<0><<<g23, 512, LDSB, stream>>>(4, abuf, abuf, 128, 128, W1T, 128, bl1, ybuf, 512,
                                          nullptr, ssum, ssq);
  bn_finalize<<<1, 512, 0, stream>>>(ssum, ssq, g1, b1, scale, shiftv);
  bn_relu<<<bn_blocks, 256, 0, stream>>>(ybuf, scale, shiftv, hbuf);

  // ---- layer 2 ----
  agg_mean512<<<agg_blocks, 256, 0, stream>>>(row_ptr, esrc, hbuf, abuf);
  hipMemsetAsync(ssum, 0, 4096, stream);
  gemmpipe<0><<<g23, 512, LDSB, stream>>>(4, abuf, hbuf, 512, 512, W2T, 1024, bl2, ybuf, 512,
                                          nullptr, ssum, ssq);
  bn_finalize<<<1, 512, 0, stream>>>(ssum, ssq, g2, b2, scale, shiftv);
  bn_relu<<<bn_blocks, 256, 0, stream>>>(ybuf, scale, shiftv, hbuf);

  // ---- layer 3 ----
  agg_mean512<<<agg_blocks, 256, 0, stream>>>(row_ptr, esrc, hbuf, abuf);
  hipMemsetAsync(ssum, 0, 4096, stream);
  gemmpipe<0><<<g23, 512, LDSB, stream>>>(4, abuf, hbuf, 512, 512, W3T, 1024, bl3, ybuf, 512,
                                          nullptr, ssum, ssq);
  bn_finalize<<<1, 512, 0, stream>>>(ssum, ssq, g3, b3, scale, shiftv);
  bn_relu<<<bn_blocks, 256, 0, stream>>>(ybuf, scale, shiftv, hbuf);

  // ---- layer 4: single GEMM, split epilogue: t4=h3@Wl4 (bf16) | d_out=h3@Wr4+bl4 (f32) ----
  gemmpipe<1><<<196 * 2, 512, LDSB, stream>>>(2, hbuf, hbuf, 512, 512, W4T, 512, bl4, ybuf, 128,
                                              (float*)d_out, nullptr, nullptr);
  agg_add121<<<(N_NODES + 3) / 4, 256, 0, stream>>>(row_ptr, esrc, ybuf, (float*)d_out);
}

// Round 13
// 638.999 us; speedup vs baseline: 1.1226x; 1.1226x over previous
//
#include <hip/hip_runtime.h>

#define N_NODES 50000
#define N_EDGES 400000
#define M_PAD   50176   // 196 * 256
#define SCAN_B  196
#define EPS_BN  1e-5f

typedef short bf16x8 __attribute__((ext_vector_type(8)));
typedef float f32x4 __attribute__((ext_vector_type(4)));

__device__ __forceinline__ float bf2f(unsigned short h) {
  union { unsigned int u; float f; } v; v.u = ((unsigned int)h) << 16; return v.f;
}
__device__ __forceinline__ unsigned short f2bf(float x) {
  union { float f; unsigned int u; } v; v.f = x;
  unsigned int r = v.u + 0x7FFFu + ((v.u >> 16) & 1u);
  return (unsigned short)(r >> 16);
}

// ---------------- CSR build ----------------
__global__ void count_deg(const int* __restrict__ dst, int* __restrict__ deg) {
  int e = blockIdx.x * 256 + threadIdx.x;
  if (e < N_EDGES) {
    int d = dst[e];
    if (d >= 0 && d < N_NODES) atomicAdd(&deg[d], 1);
  }
}

__global__ void block_sums(const int* __restrict__ deg, int* __restrict__ bsum) {
  __shared__ int sd[256];
  int b = blockIdx.x, t = threadIdx.x;
  int i = b * 256 + t;
  sd[t] = (i < N_NODES) ? deg[i] : 0;
  __syncthreads();
  for (int off = 128; off > 0; off >>= 1) {
    if (t < off) sd[t] += sd[t + off];
    __syncthreads();
  }
  if (t == 0) bsum[b] = sd[0];
}

__global__ void scan_bsums(const int* __restrict__ bsum, int* __restrict__ boff) {
  __shared__ int sd[256];
  int t = threadIdx.x;
  int v = (t < SCAN_B) ? bsum[t] : 0;
  sd[t] = v;
  __syncthreads();
  for (int off = 1; off < 256; off <<= 1) {
    int add = (t >= off) ? sd[t - off] : 0;
    __syncthreads();
    sd[t] += add;
    __syncthreads();
  }
  if (t < SCAN_B) boff[t] = sd[t] - v;  // exclusive
}

__global__ void write_rowptr(const int* __restrict__ deg, const int* __restrict__ boff,
                             int* __restrict__ row_ptr, int* __restrict__ cursor) {
  __shared__ int sd[256];
  int b = blockIdx.x, t = threadIdx.x;
  int i = b * 256 + t;
  int v = (i < N_NODES) ? deg[i] : 0;
  sd[t] = v;
  __syncthreads();
  for (int off = 1; off < 256; off <<= 1) {
    int add = (t >= off) ? sd[t - off] : 0;
    __syncthreads();
    sd[t] += add;
    __syncthreads();
  }
  if (i < N_NODES) {
    int ex = boff[b] + sd[t] - v;
    row_ptr[i] = ex;
    cursor[i]  = ex;
    if (i == N_NODES - 1) row_ptr[N_NODES] = boff[b] + sd[t];
  }
}

__global__ void scatter_edges(const int* __restrict__ src, const int* __restrict__ dst,
                              int* __restrict__ cursor, int* __restrict__ esrc) {
  int e = blockIdx.x * 256 + threadIdx.x;
  if (e < N_EDGES) {
    int d = dst[e];
    int s = src[e];
    if (d >= 0 && d < N_NODES && s >= 0 && s < N_NODES) {
      int p = atomicAdd(&cursor[d], 1);
      esrc[p] = s;
    }
  }
}

// ---------------- merged weight pack (all 5 regions, one launch) ----------------
__device__ __forceinline__ void pack_cat(const float* Wl, const float* Wr,
                                         unsigned short* WT, int idx, int Keach, int N,
                                         int Kpad) {
  int n = idx / Kpad, k = idx % Kpad;
  float v = 0.f;
  if (n < N) {
    if (k < Keach) v = Wl[k * N + n];
    else if (k < 2 * Keach) v = Wr[(k - Keach) * N + n];
  }
  WT[idx] = f2bf(v);
}

__device__ __forceinline__ void pack_one(const float* W, unsigned short* WT, int idx, int K,
                                         int N, int Kpad) {
  int n = idx / Kpad, k = idx % Kpad;
  float v = (n < N && k < K) ? W[k * N + n] : 0.f;
  WT[idx] = f2bf(v);
}

__global__ void pack_all(const float* __restrict__ Wl1, const float* __restrict__ Wr1,
                         const float* __restrict__ Wl2, const float* __restrict__ Wr2,
                         const float* __restrict__ Wl3, const float* __restrict__ Wr3,
                         const float* __restrict__ Wl4, const float* __restrict__ Wr4,
                         unsigned short* __restrict__ W1T, unsigned short* __restrict__ W2T,
                         unsigned short* __restrict__ W3T, unsigned short* __restrict__ W4T) {
  int b = blockIdx.x, t = threadIdx.x;
  if (b < 256) {
    pack_cat(Wl1, Wr1, W1T, b * 256 + t, 50, 512, 128);
  } else if (b < 2304) {
    pack_cat(Wl2, Wr2, W2T, (b - 256) * 256 + t, 512, 512, 1024);
  } else if (b < 4352) {
    pack_cat(Wl3, Wr3, W3T, (b - 2304) * 256 + t, 512, 512, 1024);
  } else if (b < 4608) {
    pack_one(Wl4, W4T, (b - 4352) * 256 + t, 512, 121, 512);
  } else {
    pack_one(Wr4, W4T + 128 * 512, (b - 4608) * 256 + t, 512, 121, 512);
  }
}

// ---------------- layer-1 input build ----------------
__global__ void prep1v(const float* __restrict__ x, const int* __restrict__ row_ptr,
                       const int* __restrict__ esrc, unsigned short* __restrict__ cat1) {
  __shared__ float part[4][64];
  int n = blockIdx.x, t = threadIdx.x;
  int w = t >> 6, lane = t & 63;
  unsigned short* row = cat1 + (long)n * 128;
  if (n >= N_NODES) {
    if (t < 64) { row[t] = 0; row[64 + t] = 0; }
    return;
  }
  int e0 = row_ptr[n], e1 = row_ptr[n + 1];
  float acc = 0.f;
  if (lane < 50) {
    for (int e = e0 + w; e < e1; e += 4) acc += x[(long)esrc[e] * 50 + lane];
  }
  part[w][lane] = acc;
  __syncthreads();
  if (t < 128) {
    if (t < 64) {
      float s = part[0][t] + part[1][t] + part[2][t] + part[3][t];
      float rdeg = (e1 > e0) ? 1.f / (float)(e1 - e0) : 0.f;
      if (t < 50) {
        row[t]      = f2bf(s * rdeg);
        row[50 + t] = f2bf(x[(long)n * 50 + t]);
      }
    } else if (t >= 100) {
      row[t] = 0;
    }
  }
}

// ---------------- mean aggregation, 512 cols: wave-per-node, 2-edge unroll ------------
__global__ void agg_mean512(const int* __restrict__ row_ptr, const int* __restrict__ esrc,
                            const unsigned short* __restrict__ h,
                            unsigned short* __restrict__ agg) {
  int n = blockIdx.x * 4 + (threadIdx.x >> 6);
  int lane = threadIdx.x & 63;
  if (n >= M_PAD) return;
  uint2* outw = (uint2*)(agg + (long)n * 512 + lane * 8);
  if (n >= N_NODES) {
    uint2 z; z.x = 0; z.y = 0;
    outw[0] = z; outw[1] = z;
    return;
  }
  int e0 = row_ptr[n], e1 = row_ptr[n + 1];
  float acc[8] = {0.f, 0.f, 0.f, 0.f, 0.f, 0.f, 0.f, 0.f};
  int e = e0;
  for (; e + 1 < e1; e += 2) {
    int s0 = esrc[e], s1 = esrc[e + 1];
    uint4 v0 = *(const uint4*)(h + (long)s0 * 512 + lane * 8);
    uint4 v1 = *(const uint4*)(h + (long)s1 * 512 + lane * 8);
    const unsigned short* p0 = (const unsigned short*)&v0;
    const unsigned short* p1 = (const unsigned short*)&v1;
#pragma unroll
    for (int j = 0; j < 8; ++j) acc[j] += bf2f(p0[j]) + bf2f(p1[j]);
  }
  if (e < e1) {
    uint4 v0 = *(const uint4*)(h + (long)esrc[e] * 512 + lane * 8);
    const unsigned short* p0 = (const unsigned short*)&v0;
#pragma unroll
    for (int j = 0; j < 8; ++j) acc[j] += bf2f(p0[j]);
  }
  float rdeg = (e1 > e0) ? 1.f / (float)(e1 - e0) : 0.f;
  uint2 r0, r1;
  r0.x = (unsigned int)f2bf(acc[0] * rdeg) | ((unsigned int)f2bf(acc[1] * rdeg) << 16);
  r0.y = (unsigned int)f2bf(acc[2] * rdeg) | ((unsigned int)f2bf(acc[3] * rdeg) << 16);
  r1.x = (unsigned int)f2bf(acc[4] * rdeg) | ((unsigned int)f2bf(acc[5] * rdeg) << 16);
  r1.y = (unsigned int)f2bf(acc[6] * rdeg) | ((unsigned int)f2bf(acc[7] * rdeg) << 16);
  outw[0] = r0;
  outw[1] = r1;
}

// ---------------- layer-4 gather-add, 121 cols ----------------
__global__ void agg_add121(const int* __restrict__ row_ptr, const int* __restrict__ esrc,
                           const unsigned short* __restrict__ t4, float* __restrict__ out) {
  int n = blockIdx.x * 4 + (threadIdx.x >> 6);
  if (n >= N_NODES) return;
  int lane = threadIdx.x & 63;
  int g = lane >> 4;
  int cl = lane & 15;
  int e0 = row_ptr[n], e1 = row_ptr[n + 1];
  float acc[8] = {0.f, 0.f, 0.f, 0.f, 0.f, 0.f, 0.f, 0.f};
  for (int e = e0 + g; e < e1; e += 4) {
    int s = esrc[e];
    uint4 v = *(const uint4*)(t4 + (long)s * 128 + cl * 8);
    const unsigned short* pv = (const unsigned short*)&v;
#pragma unroll
    for (int j = 0; j < 8; ++j) acc[j] += bf2f(pv[j]);
  }
#pragma unroll
  for (int j = 0; j < 8; ++j) {
    acc[j] += __shfl_xor(acc[j], 16);
    acc[j] += __shfl_xor(acc[j], 32);
  }
  if (g == 0) {
    float rdeg = (e1 > e0) ? 1.f / (float)(e1 - e0) : 0.f;
#pragma unroll
    for (int j = 0; j < 8; ++j) {
      int c = cl * 8 + j;
      if (c < 121) out[(long)n * 121 + c] += acc[j] * rdeg;
    }
  }
}

// ---------------- BN apply+ReLU with fused finalize (reads raw stats) ----------------
__global__ void bn_relu_f(const unsigned short* __restrict__ y, const float* __restrict__ ssum,
                          const float* __restrict__ ssq, const float* __restrict__ g,
                          const float* __restrict__ b, unsigned short* __restrict__ hout) {
  long idx = ((long)blockIdx.x * 256 + threadIdx.x) * 8;
  if (idx >= (long)M_PAD * 512) return;
  int row = (int)(idx >> 9);
  int col = (int)(idx & 511);
  unsigned short* o = hout + idx;
  if (row >= N_NODES) {
    uint4 z; z.x = 0; z.y = 0; z.z = 0; z.w = 0;
    *(uint4*)o = z;
    return;
  }
  uint4 v = *(const uint4*)(y + idx);
  unsigned short* p = (unsigned short*)&v;
  uint4 rr;
  unsigned short* q = (unsigned short*)&rr;
#pragma unroll
  for (int j = 0; j < 8; ++j) {
    int c = col + j;
    float mu  = ssum[c] * (1.f / N_NODES);
    float var = ssq[c] * (1.f / N_NODES) - mu * mu;
    float sc  = g[c] * rsqrtf(var + EPS_BN);
    float sh  = b[c] - mu * sc;
    float f = bf2f(p[j]) * sc + sh;
    q[j] = f2bf(fmaxf(f, 0.f));
  }
  *(uint4*)o = rr;
}

// ---------------- 256x256 bf16 MFMA GEMM (R9 structure + kk-outer MFMA order) --------
// A row-major [M][lda] in two column-halves (A0: k<KA0, A1: k>=KA0); B as BT[N][K].
// 8 waves (2M x 4N), per-wave C = 128x64. LDS 128KB dynamic dbuf. T2 XOR-swizzle.
// Schedule: per K-tile: issue next-tile stages (async), compute whole tile barrier-free,
// then one vmcnt(0)+s_barrier at the boundary.
// MFMA order: kk-outer so the dependent reuse of acc[m][n] is 8 MFMAs apart (not 1).
__device__ __forceinline__ void gl_lds16(const void* g, void* l) {
  __builtin_amdgcn_global_load_lds((const __attribute__((address_space(1))) unsigned int*)g,
                                   (__attribute__((address_space(3))) unsigned int*)l, 16, 0, 0);
}

__device__ __forceinline__ void stage_half(const unsigned short* srck, int ld, long row0,
                                           char* ldshalf, int q0) {
#pragma unroll
  for (int r = 0; r < 2; ++r) {
    int q = q0 + r * 8192;
    int row = q >> 7;
    int cus = ((q & 127) >> 1) ^ ((row & 7) << 3);  // inverse-swizzled source col (ushort)
    gl_lds16(srck + (row0 + row) * (long)ld + cus, ldshalf + q);
  }
}

__device__ __forceinline__ bf16x8 frag(const char* halfbase, int lr, int cb) {
  return *(const bf16x8*)(halfbase + lr * 128 + (cb ^ ((lr & 7) << 4)));
}

template <int MODE>
__launch_bounds__(512, 2)
__global__ void gemm256(int nblk, const unsigned short* __restrict__ A0,
                        const unsigned short* __restrict__ A1, int lda, int KA0,
                        const unsigned short* __restrict__ BT, int K,
                        const float* __restrict__ bias, unsigned short* __restrict__ outb,
                        int ldob, float* __restrict__ outf, float* __restrict__ ssum,
                        float* __restrict__ ssq) {
  extern __shared__ char smem[];

  // T1: bijective XCD-chunk swizzle
  const int nwg = gridDim.x, orig = blockIdx.x;
  const int xcd = orig & 7, sidx = orig >> 3;
  const int q8 = nwg >> 3, r8 = nwg & 7;
  const int wg = ((xcd < r8) ? xcd * (q8 + 1) : r8 * (q8 + 1) + (xcd - r8) * q8) + sidx;
  const int bm = wg / nblk, bn = wg - bm * nblk;
  const long brow = (long)bm * 256;
  const int bcol = bn * 256;

  const int t = threadIdx.x;
  const int lane = t & 63, wid = t >> 6;
  const int wr = (wid >> 2) * 128;  // 0 / 128
  const int wc = (wid & 3) * 64;    // 0,64,128,192
  const int hA = wr >> 7;
  const int hB = wc >> 7;
  const int lrB0 = wc & 127;        // 0 or 64 (row base within B half)
  const int l15 = lane & 15, l4 = lane >> 4;
  const int q0 = t * 16;

  f32x4 acc[8][4] = {};
  const int NT = K / 64;

  // prologue: stage tile 0 into buf 0
  {
    const unsigned short* Ap = A0;  // k0=0 < KA0 always
    stage_half(Ap, lda, brow, smem, q0);
    stage_half(Ap, lda, brow + 128, smem + 16384, q0);
    stage_half(BT, K, bcol, smem + 65536, q0);
    stage_half(BT, K, bcol + 128, smem + 65536 + 16384, q0);
  }
  asm volatile("s_waitcnt vmcnt(0)" ::: "memory");
  __builtin_amdgcn_s_barrier();

  int cur = 0;
  for (int tt = 0; tt < NT; ++tt) {
    // issue next-tile stages FIRST (async; whole tile of compute hides their latency)
    if (tt + 1 < NT) {
      const int nk0 = (tt + 1) * 64;
      const unsigned short* nAp = (nk0 < KA0) ? A0 + nk0 : A1 + (nk0 - KA0);
      const unsigned short* nBp = BT + nk0;
      char* Adst = smem + (cur ^ 1) * 32768;
      char* Bdst = smem + 65536 + (cur ^ 1) * 32768;
      stage_half(nAp, lda, brow, Adst, q0);
      stage_half(nAp, lda, brow + 128, Adst + 16384, q0);
      stage_half(nBp, K, bcol, Bdst, q0);
      stage_half(nBp, K, bcol + 128, Bdst + 16384, q0);
    }

    const char* Ard = smem + cur * 32768 + hA * 16384;
    const char* Brd = smem + 65536 + cur * 32768 + hB * 16384;

    bf16x8 bfr[4][2];
#pragma unroll
    for (int n = 0; n < 4; ++n)
#pragma unroll
      for (int kk = 0; kk < 2; ++kk)
        bfr[n][kk] = frag(Brd, lrB0 + n * 16 + l15, kk * 64 + l4 * 16);

#pragma unroll
    for (int p = 0; p < 4; ++p) {
      bf16x8 af[2][2];
#pragma unroll
      for (int mm = 0; mm < 2; ++mm)
#pragma unroll
        for (int kk = 0; kk < 2; ++kk)
          af[mm][kk] = frag(Ard, (p * 2 + mm) * 16 + l15, kk * 64 + l4 * 16);
      // kk-outer: 8 independent MFMAs between dependent acc re-uses
#pragma unroll
      for (int kk = 0; kk < 2; ++kk)
#pragma unroll
        for (int mm = 0; mm < 2; ++mm)
#pragma unroll
          for (int n = 0; n < 4; ++n)
            acc[p * 2 + mm][n] = __builtin_amdgcn_mfma_f32_16x16x32_bf16(
                af[mm][kk], bfr[n][kk], acc[p * 2 + mm][n], 0, 0, 0);
    }

    // single sync per tile: drain stages, flip buffers
    asm volatile("s_waitcnt vmcnt(0)" ::: "memory");
    __builtin_amdgcn_s_barrier();
    cur ^= 1;
  }

  // ---------------- epilogue ----------------
  float* sstat = (float*)smem;
  if (MODE == 0) {
    sstat[t] = 0.f;
    __syncthreads();
  }

#pragma unroll
  for (int m = 0; m < 8; ++m) {
    int row0 = (int)brow + wr + m * 16 + l4 * 4;
#pragma unroll
    for (int n = 0; n < 4; ++n) {
      int col = bcol + wc + n * 16 + l15;
      if (MODE == 0) {
        float bs = bias[col];
#pragma unroll
        for (int j = 0; j < 4; ++j)
          outb[(long)(row0 + j) * ldob + col] = f2bf(acc[m][n][j] + bs);
      } else {
        if (col < 128) {
#pragma unroll
          for (int j = 0; j < 4; ++j)
            outb[(long)(row0 + j) * ldob + col] = f2bf(acc[m][n][j]);
        } else {
          int c2 = col - 128;
          if (c2 < 121) {
            float bs = bias[c2];
#pragma unroll
            for (int j = 0; j < 4; ++j) {
              int row = row0 + j;
              if (row < N_NODES) outf[(long)row * 121 + c2] = acc[m][n][j] + bs;
            }
          }
        }
      }
    }
  }

  if (MODE == 0) {
#pragma unroll
    for (int n = 0; n < 4; ++n) {
      int colL = wc + n * 16 + l15;
      float bs = bias[bcol + colL];
      float s = 0.f, s2 = 0.f;
#pragma unroll
      for (int m = 0; m < 8; ++m) {
        int row0 = (int)brow + wr + m * 16 + l4 * 4;
#pragma unroll
        for (int j = 0; j < 4; ++j) {
          if (row0 + j < N_NODES) {
            float v = acc[m][n][j] + bs;
            s += v;
            s2 += v * v;
          }
        }
      }
      atomicAdd(&sstat[colL], s);
      atomicAdd(&sstat[256 + colL], s2);
    }
    __syncthreads();
    if (t < 256) {
      atomicAdd(&ssum[bcol + t], sstat[t]);
      atomicAdd(&ssq[bcol + t], sstat[256 + t]);
    }
  }
}

// ---------------- host launcher ----------------
extern "C" void kernel_launch(void* const* d_in, const int* in_sizes, int n_in, void* d_out,
                              int out_size, void* d_ws, size_t ws_size, hipStream_t stream) {
  char* p = (char*)d_ws;
  auto take = [&](size_t b) {
    char* r = p;
    p += (b + 255) & ~(size_t)255;
    return r;
  };
  int* deg      = (int*)take((size_t)N_NODES * 4);
  int* row_ptr  = (int*)take((size_t)(N_NODES + 4) * 4);
  int* cursor   = (int*)take((size_t)N_NODES * 4);
  int* esrc     = (int*)take((size_t)N_EDGES * 4);
  int* bsum     = (int*)take(256 * 4);
  int* boffb    = (int*)take(256 * 4);
  unsigned short* W1T = (unsigned short*)take((size_t)512 * 128 * 2);
  unsigned short* W2T = (unsigned short*)take((size_t)512 * 1024 * 2);
  unsigned short* W3T = (unsigned short*)take((size_t)512 * 1024 * 2);
  unsigned short* W4T = (unsigned short*)take((size_t)256 * 512 * 2);  // [Wl4^T;Wr4^T]
  float* stats  = (float*)take(3 * 1024 * 4);  // per layer: [ssum 512][ssq 512]
  unsigned short* abuf = (unsigned short*)take((size_t)M_PAD * 512 * 2);
  unsigned short* ybuf = (unsigned short*)take((size_t)M_PAD * 512 * 2);
  unsigned short* hbuf = (unsigned short*)take((size_t)M_PAD * 512 * 2);

  size_t need = (size_t)(p - (char*)d_ws);
  if (need > ws_size || n_in < 20) {
    hipMemsetAsync(d_out, 0, (size_t)out_size * 4, stream);
    return;
  }

  const float* x   = (const float*)d_in[0];
  const int*   ei  = (const int*)d_in[1];
  const int*   srcv = ei;
  const int*   dstv = ei + N_EDGES;
  const float* Wl1 = (const float*)d_in[2];
  const float* bl1 = (const float*)d_in[3];
  const float* Wr1 = (const float*)d_in[4];
  const float* Wl2 = (const float*)d_in[5];
  const float* bl2 = (const float*)d_in[6];
  const float* Wr2 = (const float*)d_in[7];
  const float* Wl3 = (const float*)d_in[8];
  const float* bl3 = (const float*)d_in[9];
  const float* Wr3 = (const float*)d_in[10];
  const float* Wl4 = (const float*)d_in[11];
  const float* bl4 = (const float*)d_in[12];
  const float* Wr4 = (const float*)d_in[13];
  const float* g1  = (const float*)d_in[14];
  const float* b1  = (const float*)d_in[15];
  const float* g2  = (const float*)d_in[16];
  const float* b2  = (const float*)d_in[17];
  const float* g3  = (const float*)d_in[18];
  const float* b3  = (const float*)d_in[19];

  float* ss1 = stats;
  float* ss2 = stats + 1024;
  float* ss3 = stats + 2048;

  // CSR (parallel scan) + single stats memset
  hipMemsetAsync(deg, 0, (size_t)N_NODES * 4, stream);
  hipMemsetAsync(stats, 0, 3 * 1024 * 4, stream);
  count_deg<<<(N_EDGES + 255) / 256, 256, 0, stream>>>(dstv, deg);
  block_sums<<<SCAN_B, 256, 0, stream>>>(deg, bsum);
  scan_bsums<<<1, 256, 0, stream>>>(bsum, boffb);
  write_rowptr<<<SCAN_B, 256, 0, stream>>>(deg, boffb, row_ptr, cursor);
  scatter_edges<<<(N_EDGES + 255) / 256, 256, 0, stream>>>(srcv, dstv, cursor, esrc);

  // weights (single merged launch)
  pack_all<<<4864, 256, 0, stream>>>(Wl1, Wr1, Wl2, Wr2, Wl3, Wr3, Wl4, Wr4, W1T, W2T, W3T,
                                     W4T);

  const int g23 = 196 * 2;           // 256-row panels x 2 col-blocks
  const size_t LDSB = 131072;
  int bn_blocks = (int)(((long)M_PAD * 512 / 8) / 256);
  int agg_blocks = M_PAD / 4;

  // ---- layer 1 ----
  prep1v<<<M_PAD, 256, 0, stream>>>(x, row_ptr, esrc, abuf);
  gemm256<0><<<g23, 512, LDSB, stream>>>(2, abuf, abuf, 128, 128, W1T, 128, bl1, ybuf, 512,
                                         nullptr, ss1, ss1 + 512);
  bn_relu_f<<<bn_blocks, 256, 0, stream>>>(ybuf, ss1, ss1 + 512, g1, b1, hbuf);

  // ---- layer 2 ----
  agg_mean512<<<agg_blocks, 256, 0, stream>>>(row_ptr, esrc, hbuf, abuf);
  gemm256<0><<<g23, 512, LDSB, stream>>>(2, abuf, hbuf, 512, 512, W2T, 1024, bl2, ybuf, 512,
                                         nullptr, ss2, ss2 + 512);
  bn_relu_f<<<bn_blocks, 256, 0, stream>>>(ybuf, ss2, ss2 + 512, g2, b2, hbuf);

  // ---- layer 3 ----
  agg_mean512<<<agg_blocks, 256, 0, stream>>>(row_ptr, esrc, hbuf, abuf);
  gemm256<0><<<g23, 512, LDSB, stream>>>(2, abuf, hbuf, 512, 512, W3T, 1024, bl3, ybuf, 512,
                                         nullptr, ss3, ss3 + 512);
  bn_relu_f<<<bn_blocks, 256, 0, stream>>>(ybuf, ss3, ss3 + 512, g3, b3, hbuf);

  // ---- layer 4: single GEMM, split epilogue: t4=h3@Wl4 (bf16) | d_out=h3@Wr4+bl4 (f32) ----
  gemm256<1><<<196, 512, LDSB, stream>>>(1, hbuf, hbuf, 512, 512, W4T, 512, bl4, ybuf, 128,
                                         (float*)d_out, nullptr, nullptr);
  agg_add121<<<(N_NODES + 3) / 4, 256, 0, stream>>>(row_ptr, esrc, ybuf, (float*)d_out);
}